// Round 9
// baseline (169.000 us; speedup 1.0000x reference)
//
#include <hip/hip_runtime.h>
#include <stdint.h>

// Hard voxelization, MI355X. f32x4 points -> f32 concat out:
//   voxels[60000,32,4], coors[60000,3](z,y,x), npv[60000], voxel_num[1].
//
// R8 forensics: k_build at the scattered-atomic ceiling (63MB/46us = 1.37TB/s
// of distinct 64B lines; one atomic per voxel is the floor). Hidden #2 cost:
// k_assign's random h64 read+write (~88MB scattered). R9 removes it:
//  - pflat[p] (sequential) gives assign its coors; assign writes only
//    contiguous arrays (cnt2=1, repidx, coors). h64 is read-only after build.
//  - dup points (~6K) get vid by rank: rep r from h64, then
//    partials[r>>12] + popcount(flagbits < r).  (list used for dups only.)

#define GX 1024
#define GY 1024
#define GZ 40
#define MAXV 60000
#define MAXP 32
#define HBITS 21
#define HSIZE (1u << HBITS)
#define HMASK (HSIZE - 1u)
#define CANDBIT (1 << 30)
#define TB 256
#define ITEMS 16
#define TILE (TB * ITEMS)  // 4096
#define EMPTY64 0xFFFFFFFFFFFFFFFFull

#define OFF_COORS ((size_t)MAXV * MAXP * 4)            // 7,680,000
#define OFF_NPV   (OFF_COORS + (size_t)MAXV * 3)       // 7,860,000
#define OFF_VNUM  (OFF_NPV + (size_t)MAXV)             // 7,920,000

typedef unsigned long long u64;

__device__ __forceinline__ unsigned hashf(int flat) {
    return ((unsigned)flat * 2654435761u) >> (32 - HBITS);
}

// ---- init: hash=EMPTY, cnt2=0, contested=0, coors region=0 (~19MB) ----
__global__ void k_init(u64* __restrict__ h64, int* __restrict__ cnt2,
                       unsigned char* __restrict__ contested, int n,
                       float* __restrict__ oF) {
    int i = blockIdx.x * blockDim.x + threadIdx.x;
    int stride = gridDim.x * blockDim.x;
    for (int j = i; j < (int)HSIZE; j += stride) h64[j] = EMPTY64;
    for (int j = i; j < MAXV; j += stride) cnt2[j] = 0;
    int nw = (n + 3) / 4;
    unsigned* c4 = (unsigned*)contested;
    for (int j = i; j < nw; j += stride) c4[j] = 0;
    for (int j = i; j < MAXV * 3; j += stride) oF[OFF_COORS + j] = 0.f;
}

__device__ __forceinline__ int voxel_flat(float4 pt) {
    // identical IEEE f32 math to reference
    float fx = floorf((pt.x + 51.2f) / 0.1f);
    float fy = floorf((pt.y + 51.2f) / 0.1f);
    float fz = floorf((pt.z + 5.0f) / 0.2f);
    int cx = (int)fx, cy = (int)fy, cz = (int)fz;
    bool valid = (fx >= 0.f) & (cx < GX) & (fy >= 0.f) & (cy < GY) & (fz >= 0.f) & (cz < GZ);
    return valid ? (cx * GY + cy) * GZ + cz : -1;
}

// ---- build: 1 CAS typ.; pslot = slot|CANDBIT(candidate); pflat = flat ----
__global__ __launch_bounds__(TB) void k_build(const float4* __restrict__ pts, int n,
                                              u64* __restrict__ h64,
                                              int* __restrict__ pslot,
                                              int* __restrict__ pflat,
                                              unsigned char* __restrict__ contested) {
    int p = blockIdx.x * blockDim.x + threadIdx.x;
    if (p >= n) return;
    float4 pt = pts[p];
    int flat = voxel_flat(pt);
    pflat[p] = flat;
    if (flat < 0) { pslot[p] = -1; return; }
    u64 want = ((u64)(unsigned)flat << 32) | (unsigned)p;
    unsigned slot = hashf(flat);
    int res = -1;
    for (int probe = 0; probe < 4096; probe++) {          // bounded: hang-proof
        u64 cur = atomicCAS(&h64[slot], EMPTY64, want);
        if (cur == EMPTY64) { res = (int)slot | CANDBIT; break; }  // insert winner
        if ((unsigned)(cur >> 32) == (unsigned)flat) {    // existing voxel
            if ((unsigned)cur > (unsigned)p) {
                u64 old = atomicMin(&h64[slot], want);    // key equal -> compares rep
                unsigned oldrep = (unsigned)old;
                if (oldrep > (unsigned)p) {               // we really lowered it
                    contested[oldrep] = 1;                // previous holder dethroned
                    res = (int)slot | CANDBIT;
                } else {
                    res = (int)slot;
                }
            } else {
                res = (int)slot;
            }
            break;
        }
        slot = (slot + 1u) & HMASK;
    }
    pslot[p] = res;
}

// ---- partials: flag = candidate && !contested -> flagbits + block sums ----
__global__ __launch_bounds__(TB) void k_partials(const int* __restrict__ pslot,
                                                 const unsigned char* __restrict__ contested,
                                                 int n, u64* __restrict__ flagbits,
                                                 int* __restrict__ partials) {
    __shared__ int sh[TB];
    int t = threadIdx.x;
    int base = blockIdx.x * TILE;
    int s = 0;
    #pragma unroll
    for (int j = 0; j < ITEMS; j++) {
        int i = base + j * TB + t;
        int pred = 0;
        if (i < n) {
            int raw = pslot[i];
            pred = (raw >= 0) && (raw & CANDBIT) && !contested[i];
        }
        u64 m = __ballot(pred);
        if ((t & 63) == 0) flagbits[i >> 6] = m;   // i is 64-aligned at lane 0
        s += pred;
    }
    sh[t] = s;
    __syncthreads();
    for (int off = TB / 2; off > 0; off >>= 1) {
        if (t < off) sh[t] += sh[t + off];
        __syncthreads();
    }
    if (t == 0) partials[blockIdx.x] = sh[0];
}

__global__ __launch_bounds__(1024) void k_scan(int* __restrict__ partials, int nb,
                                               float* __restrict__ oF) {
    __shared__ int sh[1024];
    int t = threadIdx.x;
    int v = (t < nb) ? partials[t] : 0;
    sh[t] = v;
    __syncthreads();
    for (int off = 1; off < 1024; off <<= 1) {
        int add = (t >= off) ? sh[t - off] : 0;
        __syncthreads();
        sh[t] += add;
        __syncthreads();
    }
    if (t < nb) partials[t] = sh[t] - v;  // exclusive block offsets
    if (t == 1023) {
        int total = sh[1023];
        if (total > MAXV) total = MAXV;
        oF[OFF_VNUM] = (float)total;      // voxel_num
    }
}

// ---- assign: vid; coors from pflat; cnt2=1, repidx — ALL contiguous writes ----
__global__ __launch_bounds__(TB) void k_assign(const u64* __restrict__ flagbits,
                                               const int* __restrict__ partials,
                                               const int* __restrict__ pflat,
                                               int* __restrict__ cnt2,
                                               int* __restrict__ repidx,
                                               float* __restrict__ oF) {
    __shared__ int sh[TB];
    int t = threadIdx.x;
    int base = blockIdx.x * TILE;
    unsigned bits = (unsigned)((flagbits[(base >> 6) + (t >> 2)] >> ((t & 3) * 16)) & 0xFFFFull);
    int s = __popc(bits);
    sh[t] = s;
    __syncthreads();
    for (int off = 1; off < TB; off <<= 1) {
        int add = (t >= off) ? sh[t - off] : 0;
        __syncthreads();
        sh[t] += add;
        __syncthreads();
    }
    int vid = partials[blockIdx.x] + (sh[t] - s);
    int ibase = base + t * ITEMS;
    #pragma unroll
    for (int j = 0; j < ITEMS; j++) {
        if ((bits >> j) & 1) {
            if (vid < MAXV) {
                int i = ibase + j;
                int flat = pflat[i];
                int zc = flat % GZ;
                int t2 = flat / GZ;
                int yc = t2 % GY;
                int xc = t2 / GY;
                size_t cOff = OFF_COORS + (size_t)vid * 3;
                oF[cOff + 0] = (float)zc;
                oF[cOff + 1] = (float)yc;
                oF[cOff + 2] = (float)xc;
                cnt2[vid] = 1;       // rep occupies row 0
                repidx[vid] = i;     // contiguous (no list-line scatter)
            }
            vid++;
        }
    }
}

// ---- scatter: dup points (~6K) only; vid via rank(rep) popcount ----
__global__ void k_scatter(const int* __restrict__ pslot,
                          const unsigned char* __restrict__ contested,
                          const u64* __restrict__ h64,
                          const u64* __restrict__ flagbits,
                          const int* __restrict__ partials,
                          int* __restrict__ cnt2, int* __restrict__ list, int n) {
    int p = blockIdx.x * blockDim.x + threadIdx.x;
    if (p >= n) return;
    int raw = pslot[p];
    if (raw < 0) return;
    if ((raw & CANDBIT) && !contested[p]) return;   // first-occurrence: already placed
    unsigned r = (unsigned)h64[raw & HMASK];        // final rep of this voxel
    // vid = rank of r among flagged points
    int blk = (int)(r >> 12);                       // TILE = 4096
    int vid = partials[blk];
    int wbase = blk << 6;                           // (blk*4096)/64
    int we = (int)(r >> 6);
    for (int w = wbase; w < we; w++) vid += __popcll(flagbits[w]);
    unsigned tail = r & 63u;
    if (tail) vid += __popcll(flagbits[we] & ((1ull << tail) - 1ull));
    if (vid >= MAXV) return;                        // capped voxel
    int pos = atomicAdd(&cnt2[vid], 1);             // >= 1 (rep holds row 0)
    if (pos < MAXP) list[vid * MAXP + pos] = p;
}

// ---- emit: all 32 rows per voxel (zeros beyond m); row0 = repidx; npv ----
__global__ void k_emit(const float4* __restrict__ pts, const int* __restrict__ cnt2,
                       const int* __restrict__ repidx, const int* __restrict__ list,
                       float4* __restrict__ outVox, float* __restrict__ oF) {
    int vid = blockIdx.x * blockDim.x + threadIdx.x;
    if (vid >= MAXV) return;
    int m = cnt2[vid];
    if (m > MAXP) m = MAXP;
    oF[OFF_NPV + vid] = (float)m;
    const float4 zero = make_float4(0.f, 0.f, 0.f, 0.f);
    const int* lst = &list[vid * MAXP];
    int prev = -1;
    for (int r = 0; r < MAXP; r++) {
        float4 row = zero;
        if (r == 0 && m > 0) {
            row = pts[repidx[vid]];        // rep = provably min index
        } else if (r < m) {                // dups in ascending original order
            int best = 0x7FFFFFFF;
            for (int j = 1; j < m; j++) {
                int v = lst[j];
                if (v > prev && v < best) best = v;
            }
            prev = best;
            row = pts[best];               // bit-exact f32x4 row copy
        }
        outVox[vid * MAXP + r] = row;
    }
}

extern "C" void kernel_launch(void* const* d_in, const int* in_sizes, int n_in,
                              void* d_out, int out_size, void* d_ws, size_t ws_size,
                              hipStream_t stream) {
    int n = in_sizes[0] / 4;                       // 1,200,000
    const float4* pts = (const float4*)d_in[0];

    int tb = 256;
    int nbp = (n + tb - 1) / tb;
    int nb = (n + TILE - 1) / TILE;                // 293
    int nwords = (nb * TILE) / 64;                 // flagbits words (tile-padded)

    // ws layout, ~35 MB
    char* base = (char*)d_ws;
    size_t o = 0;
    int* partials = (int*)(base + o);  o += 4096 * 4;
    int* cnt2     = (int*)(base + o);  o += (size_t)MAXV * 4;
    int* repidx   = (int*)(base + o);  o += (size_t)MAXV * 4;
    o = (o + 255) & ~(size_t)255;
    u64* flagbits = (u64*)(base + o);  o += (size_t)nwords * 8;
    o = (o + 255) & ~(size_t)255;
    unsigned char* contested = (unsigned char*)(base + o);  o += ((size_t)n + 255) & ~(size_t)255;
    u64* h64      = (u64*)(base + o);  o += (size_t)HSIZE * 8;
    int* pslot    = (int*)(base + o);  o += (size_t)n * 4;
    int* pflat    = (int*)(base + o);  o += (size_t)n * 4;
    int* list     = (int*)(base + o);  o += (size_t)MAXV * MAXP * 4;

    float* oF = (float*)d_out;

    k_init<<<2048, tb, 0, stream>>>(h64, cnt2, contested, n, oF);
    k_build<<<nbp, tb, 0, stream>>>(pts, n, h64, pslot, pflat, contested);
    k_partials<<<nb, TB, 0, stream>>>(pslot, contested, n, flagbits, partials);
    k_scan<<<1, 1024, 0, stream>>>(partials, nb, oF);
    k_assign<<<nb, TB, 0, stream>>>(flagbits, partials, pflat, cnt2, repidx, oF);
    k_scatter<<<nbp, tb, 0, stream>>>(pslot, contested, h64, flagbits, partials, cnt2, list, n);
    k_emit<<<(MAXV + tb - 1) / tb, tb, 0, stream>>>(pts, cnt2, repidx, list, (float4*)d_out, oF);
}